// Round 1
// baseline (471.596 us; speedup 1.0000x reference)
//
#include <hip/hip_runtime.h>

// SinkhornOT fused kernel — round 0 baseline.
// B=2048, K=M=64, D=256, eps=0.05, 20 sinkhorn iters, 3 MESH iters.
//
// Plan: prep kernel transposes W1,W2 -> bf16 (ws). Main kernel: 1 block per
// batch, 256 threads (4 waves). LDS: bufQ/bufR 32KB each (X->H->P bf16 tiles,
// XOR-swizzled), later reused as T-tile (bufQ) and C-tile (bufR), 64x65 f32.

typedef __attribute__((ext_vector_type(8))) short s16x8;
typedef __attribute__((ext_vector_type(4))) float f32x4;

__device__ __forceinline__ unsigned short f2bf(float x) {  // RNE f32->bf16
  unsigned u = __builtin_bit_cast(unsigned, x);
  u += 0x7fffu + ((u >> 16) & 1u);
  return (unsigned short)(u >> 16);
}
__device__ __forceinline__ float bf2f(unsigned short h) {
  return __builtin_bit_cast(float, ((unsigned)h) << 16);
}

#define MFMA16(a, b, c) __builtin_amdgcn_mfma_f32_16x16x32_bf16((a), (b), (c), 0, 0, 0)

__global__ void __launch_bounds__(256)
prep_w_kernel(const float* __restrict__ W1, const float* __restrict__ W2,
              short* __restrict__ W1t, short* __restrict__ W2t) {
  int i = blockIdx.x * 256 + threadIdx.x;   // 65536 threads exactly
  int d = i >> 8, e = i & 255;
  W1t[e * 256 + d] = (short)f2bf(W1[i]);
  W2t[e * 256 + d] = (short)f2bf(W2[i]);
}

__global__ void __launch_bounds__(256, 2)
sinkhorn_fused(const float* __restrict__ slots_q, const float* __restrict__ slots_r,
               const float* __restrict__ mask_r,
               const short* __restrict__ W1t, const short* __restrict__ W2t,
               const float* __restrict__ b1, const float* __restrict__ b2,
               float* __restrict__ out) {
  __shared__ char smem[65536];
  char* bufQ = smem;            // 32KB: Xq -> Hq -> Pq ; later T tile + arrays
  char* bufR = smem + 32768;    // 32KB: Xr -> Hr -> Pr ; later C tile
  float* Tt = (float*)bufQ;                  // [64][65] f32 (16640 B)
  float* Ct = (float*)bufR;                  // [64][65] f32
  float* u_arr  = (float*)(bufQ + 16640);    // 64 f32
  float* w_arr  = u_arr + 64;                // 64 f32
  float* r2_arr = w_arr + 64;                // 64 f32
  float* red_arr = r2_arr + 64;              // 4 f32

  const int b    = blockIdx.x;
  const int tid  = threadIdx.x;
  const int wv   = tid >> 6;
  const int lane = tid & 63;
  const int l15  = lane & 15;
  const int lhi  = lane >> 4;

  // ---------- stage slots (f32 -> bf16, swizzled row-major [64][512B]) ----------
  {
    const float* sq = slots_q + (size_t)b * 16384;
    const float* sr = slots_r + (size_t)b * 16384;
#pragma unroll
    for (int i = 0; i < 16; ++i) {
      int idx4 = tid + 256 * i;               // float4 index
      int row = idx4 >> 6;                    // 64 float4 per row
      int colb = (idx4 & 63) * 8;             // byte offset of 4 bf16
      int byte = row * 512 + (colb ^ ((row & 7) << 4));
      float4 vq = *(const float4*)(sq + idx4 * 4);
      float4 vr = *(const float4*)(sr + idx4 * 4);
      unsigned q_lo = (unsigned)f2bf(vq.x) | ((unsigned)f2bf(vq.y) << 16);
      unsigned q_hi = (unsigned)f2bf(vq.z) | ((unsigned)f2bf(vq.w) << 16);
      unsigned r_lo = (unsigned)f2bf(vr.x) | ((unsigned)f2bf(vr.y) << 16);
      unsigned r_hi = (unsigned)f2bf(vr.z) | ((unsigned)f2bf(vr.w) << 16);
      *(uint2*)(bufQ + byte) = make_uint2(q_lo, q_hi);
      *(uint2*)(bufR + byte) = make_uint2(r_lo, r_hi);
    }
  }
  __syncthreads();

  const int arow  = wv * 16 + l15;        // A-frag row (this wave's strip)
  const int abase = arow * 512;
  const int asw   = (arow & 7) << 4;
  const int ksub  = lhi * 16;             // byte sub-offset within 64B k-step
  const int weidx0 = l15 * 256 + lhi * 8; // W-frag element base (n=0)

  f32x4 accQ[16], accR[16];
  float bias[16];
  const f32x4 z4 = {0.f, 0.f, 0.f, 0.f};

  // ================= GEMM1: H = relu(X*W1 + b1) =================
#pragma unroll
  for (int n = 0; n < 16; ++n) { bias[n] = b1[n * 16 + l15]; accQ[n] = z4; accR[n] = z4; }
#pragma unroll
  for (int ks = 0; ks < 8; ++ks) {
    int koffb = ks * 64 + ksub;
    int abyte = abase + (koffb ^ asw);
    s16x8 aQ = *(const s16x8*)(bufQ + abyte);
    s16x8 aR = *(const s16x8*)(bufR + abyte);
    const short* wp = W1t + weidx0 + ks * 32;
#pragma unroll
    for (int n = 0; n < 16; ++n) {
      s16x8 bW = *(const s16x8*)(wp + n * 4096);
      accQ[n] = MFMA16(aQ, bW, accQ[n]);
      accR[n] = MFMA16(aR, bW, accR[n]);
    }
  }
  // write H (own rows only -> no cross-wave hazard, no barrier needed)
#pragma unroll
  for (int n = 0; n < 16; ++n) {
#pragma unroll
    for (int j = 0; j < 4; ++j) {
      int row = wv * 16 + lhi * 4 + j;
      int colb = (n * 16 + l15) * 2;
      int byte = row * 512 + (colb ^ ((row & 7) << 4));
      *(unsigned short*)(bufQ + byte) = f2bf(fmaxf(accQ[n][j] + bias[n], 0.0f));
      *(unsigned short*)(bufR + byte) = f2bf(fmaxf(accR[n][j] + bias[n], 0.0f));
    }
  }

  // ================= GEMM2: P = H*W2 + b2 (+ row norms) =================
#pragma unroll
  for (int n = 0; n < 16; ++n) { bias[n] = b2[n * 16 + l15]; accQ[n] = z4; accR[n] = z4; }
#pragma unroll
  for (int ks = 0; ks < 8; ++ks) {
    int koffb = ks * 64 + ksub;
    int abyte = abase + (koffb ^ asw);
    s16x8 aQ = *(const s16x8*)(bufQ + abyte);
    s16x8 aR = *(const s16x8*)(bufR + abyte);
    const short* wp = W2t + weidx0 + ks * 32;
#pragma unroll
    for (int n = 0; n < 16; ++n) {
      s16x8 bW = *(const s16x8*)(wp + n * 4096);
      accQ[n] = MFMA16(aQ, bW, accQ[n]);
      accR[n] = MFMA16(aR, bW, accR[n]);
    }
  }
  float nQ[4] = {0.f, 0.f, 0.f, 0.f}, nR[4] = {0.f, 0.f, 0.f, 0.f};
#pragma unroll
  for (int n = 0; n < 16; ++n) {
#pragma unroll
    for (int j = 0; j < 4; ++j) {
      int row = wv * 16 + lhi * 4 + j;
      int colb = (n * 16 + l15) * 2;
      int byte = row * 512 + (colb ^ ((row & 7) << 4));
      unsigned short hq = f2bf(accQ[n][j] + bias[n]);
      unsigned short hr = f2bf(accR[n][j] + bias[n]);
      *(unsigned short*)(bufQ + byte) = hq;
      *(unsigned short*)(bufR + byte) = hr;
      float fq = bf2f(hq), fr = bf2f(hr);
      nQ[j] += fq * fq;
      nR[j] += fr * fr;
    }
  }
#pragma unroll
  for (int d = 1; d < 16; d <<= 1) {
#pragma unroll
    for (int j = 0; j < 4; ++j) { nQ[j] += __shfl_xor(nQ[j], d); nR[j] += __shfl_xor(nR[j], d); }
  }
  __syncthreads();   // all P tiles staged

  // ================= qr GEMM: qr[k][m] = sum_d Pq[k][d]*Pr[m][d] =================
  f32x4 accC[4];
#pragma unroll
  for (int n = 0; n < 4; ++n) accC[n] = z4;
#pragma unroll
  for (int ks = 0; ks < 8; ++ks) {
    int koffb = ks * 64 + ksub;
    int abyte = abase + (koffb ^ asw);
    s16x8 aQ = *(const s16x8*)(bufQ + abyte);
#pragma unroll
    for (int n = 0; n < 4; ++n) {
      int rrow = n * 16 + l15;
      int bbyte = rrow * 512 + (koffb ^ ((rrow & 7) << 4));
      s16x8 bR = *(const s16x8*)(bufR + bbyte);
      accC[n] = MFMA16(aQ, bR, accC[n]);
    }
  }
  __syncthreads();   // all LDS frag reads done -> tiles reusable

  if (l15 == 0) {
#pragma unroll
    for (int j = 0; j < 4; ++j) r2_arr[wv * 16 + lhi * 4 + j] = nR[j];
  }
  if (tid < 64) w_arr[tid] = __logf(fmaxf(mask_r[(size_t)b * 64 + tid], 1e-8f));
  __syncthreads();

  // C tile: C = sqrt(max(q2 + r2 - 2*qr, 0))
#pragma unroll
  for (int n = 0; n < 4; ++n) {
#pragma unroll
    for (int j = 0; j < 4; ++j) {
      int k = wv * 16 + lhi * 4 + j;
      int m = n * 16 + l15;
      float d2 = nQ[j] + r2_arr[m] - 2.0f * accC[n][j];
      Ct[k * 65 + m] = sqrtf(fmaxf(d2, 0.0f));
    }
  }
  __syncthreads();

  // C -> global (coalesced)
  {
    float* Cout = out + (2048 + 8388608) + (size_t)b * 4096;
#pragma unroll
    for (int i = 0; i < 16; ++i) {
      int idx = tid + 256 * i;
      Cout[idx] = Ct[(idx >> 6) * 65 + (idx & 63)];
    }
  }

  // ================= Sinkhorn (log domain, u/w parametrization) =================
  // u = lmq + la, w = lmr + lb.  u = -lse_m(-C/eps + w); w = -lse_k(-C/eps + u).
  // T = exp(-C/eps + u + w).  Algebraically identical to the reference.
  const int rk = tid >> 2;
  const int g  = tid & 3;
  const int e0 = g * 16;

  for (int it = 0; it < 20; ++it) {
    {
      float v[16];
#pragma unroll
      for (int i = 0; i < 16; ++i) v[i] = Ct[rk * 65 + e0 + i] * -20.0f + w_arr[e0 + i];
      float mx = v[0];
#pragma unroll
      for (int i = 1; i < 16; ++i) mx = fmaxf(mx, v[i]);
      float s = 0.0f;
#pragma unroll
      for (int i = 0; i < 16; ++i) s += __expf(v[i] - mx);
#pragma unroll
      for (int d = 1; d < 4; d <<= 1) {
        float mo = __shfl_xor(mx, d), so = __shfl_xor(s, d);
        float nm = fmaxf(mx, mo);
        s = s * __expf(mx - nm) + so * __expf(mo - nm);
        mx = nm;
      }
      if (g == 0) u_arr[rk] = -(mx + __logf(s));
    }
    __syncthreads();
    {
      float v[16];
#pragma unroll
      for (int i = 0; i < 16; ++i) v[i] = Ct[(e0 + i) * 65 + rk] * -20.0f + u_arr[e0 + i];
      float mx = v[0];
#pragma unroll
      for (int i = 1; i < 16; ++i) mx = fmaxf(mx, v[i]);
      float s = 0.0f;
#pragma unroll
      for (int i = 0; i < 16; ++i) s += __expf(v[i] - mx);
#pragma unroll
      for (int d = 1; d < 4; d <<= 1) {
        float mo = __shfl_xor(mx, d), so = __shfl_xor(s, d);
        float nm = fmaxf(mx, mo);
        s = s * __expf(mx - nm) + so * __expf(mo - nm);
        mx = nm;
      }
      if (g == 0) w_arr[rk] = -(mx + __logf(s));
    }
    __syncthreads();
  }

  // T = exp(-C/eps + u + w)
  {
    float uk = u_arr[rk];
#pragma unroll
    for (int i = 0; i < 16; ++i) {
      int m = e0 + i;
      Tt[rk * 65 + m] = __expf(Ct[rk * 65 + m] * -20.0f + uk + w_arr[m]);
    }
  }
  // MESH: T <- (T*T)/rowsum, then /colsum, x3
  for (int it = 0; it < 3; ++it) {
    {
      float v[16]; float s = 0.0f;
#pragma unroll
      for (int i = 0; i < 16; ++i) { float x = Tt[rk * 65 + e0 + i]; v[i] = x * x; s += v[i]; }
      s += __shfl_xor(s, 1); s += __shfl_xor(s, 2);
      float inv = 1.0f / (s + 1e-8f);
#pragma unroll
      for (int i = 0; i < 16; ++i) Tt[rk * 65 + e0 + i] = v[i] * inv;
    }
    __syncthreads();
    {
      float v[16]; float s = 0.0f;
#pragma unroll
      for (int i = 0; i < 16; ++i) { float x = Tt[(e0 + i) * 65 + rk]; v[i] = x; s += x; }
      s += __shfl_xor(s, 1); s += __shfl_xor(s, 2);
      float inv = 1.0f / (s + 1e-8f);
#pragma unroll
      for (int i = 0; i < 16; ++i) Tt[(e0 + i) * 65 + rk] = v[i] * inv;
    }
    __syncthreads();
  }

  // transport cost + similarity
  {
    float part = 0.0f;
#pragma unroll
    for (int i = 0; i < 16; ++i) part += Tt[rk * 65 + e0 + i] * Ct[rk * 65 + e0 + i];
#pragma unroll
    for (int d = 1; d < 64; d <<= 1) part += __shfl_xor(part, d);
    if (lane == 0) red_arr[wv] = part;
  }
  __syncthreads();
  if (tid == 0) {
    float tc = red_arr[0] + red_arr[1] + red_arr[2] + red_arr[3];
    out[(2048 + 16777216) + b] = tc;
    out[b] = 1.0f / (1.0f + __expf(tc));
  }
  // T_hard -> global (coalesced)
  {
    float* Tout = out + 2048 + (size_t)b * 4096;
#pragma unroll
    for (int i = 0; i < 16; ++i) {
      int idx = tid + 256 * i;
      Tout[idx] = Tt[(idx >> 6) * 65 + (idx & 63)];
    }
  }
}

extern "C" void kernel_launch(void* const* d_in, const int* in_sizes, int n_in,
                              void* d_out, int out_size, void* d_ws, size_t ws_size,
                              hipStream_t stream) {
  const float* slots_q = (const float*)d_in[0];
  const float* slots_r = (const float*)d_in[1];
  // d_in[2] = mask_q: provably cancels out of T/T_hard/C/cost (row-rescaling
  // invariance of Sinkhorn); masks are all-ones in this problem anyway.
  const float* mask_r = (const float*)d_in[3];
  const float* W1 = (const float*)d_in[4];
  const float* b1 = (const float*)d_in[5];
  const float* W2 = (const float*)d_in[6];
  const float* b2 = (const float*)d_in[7];

  short* W1t = (short*)d_ws;            // 256x256 bf16 transposed
  short* W2t = W1t + 65536;

  prep_w_kernel<<<256, 256, 0, stream>>>(W1, W2, W1t, W2t);
  sinkhorn_fused<<<2048, 256, 0, stream>>>(slots_q, slots_r, mask_r, W1t, W2t,
                                           b1, b2, (float*)d_out);
}

// Round 2
// 432.524 us; speedup vs baseline: 1.0903x; 1.0903x over previous
//
#include <hip/hip_runtime.h>

// SinkhornOT — round 1: split into (A) MFMA-dense projection+cost kernel and
// (B) high-occupancy Sinkhorn/MESH solver with C held in registers.
// B=2048, K=M=64, D=256, eps=0.05, 20 sinkhorn iters, 3 MESH iters.

typedef __attribute__((ext_vector_type(8))) short s16x8;
typedef __attribute__((ext_vector_type(4))) float f32x4;

#define OFF_T  2048
#define OFF_C  (2048 + 2048 * 4096)
#define OFF_TC (2048 + 2 * 2048 * 4096)

__device__ __forceinline__ unsigned short f2bf(float x) {  // RNE f32->bf16
  unsigned u = __builtin_bit_cast(unsigned, x);
  u += 0x7fffu + ((u >> 16) & 1u);
  return (unsigned short)(u >> 16);
}
__device__ __forceinline__ float bf2f(unsigned short h) {
  return __builtin_bit_cast(float, ((unsigned)h) << 16);
}

#define MFMA16(a, b, c) __builtin_amdgcn_mfma_f32_16x16x32_bf16((a), (b), (c), 0, 0, 0)

__global__ void __launch_bounds__(256)
prep_w_kernel(const float* __restrict__ W1, const float* __restrict__ W2,
              short* __restrict__ W1t, short* __restrict__ W2t) {
  int i = blockIdx.x * 256 + threadIdx.x;   // 65536 threads exactly
  int d = i >> 8, e = i & 255;
  W1t[e * 256 + d] = (short)f2bf(W1[i]);
  W2t[e * 256 + d] = (short)f2bf(W2[i]);
}

// ======================= Kernel A: projections + cdist =======================
__global__ void __launch_bounds__(256, 2)
proj_cost_kernel(const float* __restrict__ slots_q, const float* __restrict__ slots_r,
                 const short* __restrict__ W1t, const short* __restrict__ W2t,
                 const float* __restrict__ b1, const float* __restrict__ b2,
                 float* __restrict__ out) {
  __shared__ char smem[65536];
  char* bufQ = smem;            // 32KB: Xq -> Hq -> Pq (bf16, swizzled); later r2 array
  char* bufR = smem + 32768;    // 32KB: Xr -> Hr -> Pr

  const int b    = blockIdx.x;
  const int tid  = threadIdx.x;
  const int wv   = tid >> 6;
  const int lane = tid & 63;
  const int l15  = lane & 15;
  const int lhi  = lane >> 4;

  // ---------- stage slots (f32 -> bf16, swizzled row-major [64][512B]) ----------
  {
    const float* sq = slots_q + (size_t)b * 16384;
    const float* sr = slots_r + (size_t)b * 16384;
#pragma unroll
    for (int i = 0; i < 16; ++i) {
      int idx4 = tid + 256 * i;               // float4 index
      int row = idx4 >> 6;                    // 64 float4 per row
      int colb = (idx4 & 63) * 8;             // byte offset of 4 bf16
      int byte = row * 512 + (colb ^ ((row & 7) << 4));
      float4 vq = *(const float4*)(sq + idx4 * 4);
      float4 vr = *(const float4*)(sr + idx4 * 4);
      unsigned q_lo = (unsigned)f2bf(vq.x) | ((unsigned)f2bf(vq.y) << 16);
      unsigned q_hi = (unsigned)f2bf(vq.z) | ((unsigned)f2bf(vq.w) << 16);
      unsigned r_lo = (unsigned)f2bf(vr.x) | ((unsigned)f2bf(vr.y) << 16);
      unsigned r_hi = (unsigned)f2bf(vr.z) | ((unsigned)f2bf(vr.w) << 16);
      *(uint2*)(bufQ + byte) = make_uint2(q_lo, q_hi);
      *(uint2*)(bufR + byte) = make_uint2(r_lo, r_hi);
    }
  }
  __syncthreads();

  const int arow  = wv * 16 + l15;        // A-frag row (this wave's strip)
  const int abase = arow * 512;
  const int asw   = (arow & 7) << 4;
  const int ksub  = lhi * 16;             // byte sub-offset within 64B k-step
  const int weidx0 = l15 * 256 + lhi * 8; // W-frag element base (n=0)

  f32x4 accQ[16], accR[16];
  float bias[16];
  const f32x4 z4 = {0.f, 0.f, 0.f, 0.f};

  // ================= GEMM1: H = relu(X*W1 + b1) =================
#pragma unroll
  for (int n = 0; n < 16; ++n) { bias[n] = b1[n * 16 + l15]; accQ[n] = z4; accR[n] = z4; }
#pragma unroll
  for (int ks = 0; ks < 8; ++ks) {
    int koffb = ks * 64 + ksub;
    int abyte = abase + (koffb ^ asw);
    s16x8 aQ = *(const s16x8*)(bufQ + abyte);
    s16x8 aR = *(const s16x8*)(bufR + abyte);
    const short* wp = W1t + weidx0 + ks * 32;
#pragma unroll
    for (int n = 0; n < 16; ++n) {
      s16x8 bW = *(const s16x8*)(wp + n * 4096);
      accQ[n] = MFMA16(aQ, bW, accQ[n]);
      accR[n] = MFMA16(aR, bW, accR[n]);
    }
  }
  // write H (own rows only -> no cross-wave hazard, no barrier needed)
#pragma unroll
  for (int n = 0; n < 16; ++n) {
#pragma unroll
    for (int j = 0; j < 4; ++j) {
      int row = wv * 16 + lhi * 4 + j;
      int colb = (n * 16 + l15) * 2;
      int byte = row * 512 + (colb ^ ((row & 7) << 4));
      *(unsigned short*)(bufQ + byte) = f2bf(fmaxf(accQ[n][j] + bias[n], 0.0f));
      *(unsigned short*)(bufR + byte) = f2bf(fmaxf(accR[n][j] + bias[n], 0.0f));
    }
  }

  // ================= GEMM2: P = H*W2 + b2 (+ row norms) =================
#pragma unroll
  for (int n = 0; n < 16; ++n) { bias[n] = b2[n * 16 + l15]; accQ[n] = z4; accR[n] = z4; }
#pragma unroll
  for (int ks = 0; ks < 8; ++ks) {
    int koffb = ks * 64 + ksub;
    int abyte = abase + (koffb ^ asw);
    s16x8 aQ = *(const s16x8*)(bufQ + abyte);
    s16x8 aR = *(const s16x8*)(bufR + abyte);
    const short* wp = W2t + weidx0 + ks * 32;
#pragma unroll
    for (int n = 0; n < 16; ++n) {
      s16x8 bW = *(const s16x8*)(wp + n * 4096);
      accQ[n] = MFMA16(aQ, bW, accQ[n]);
      accR[n] = MFMA16(aR, bW, accR[n]);
    }
  }
  float nQ[4] = {0.f, 0.f, 0.f, 0.f}, nR[4] = {0.f, 0.f, 0.f, 0.f};
#pragma unroll
  for (int n = 0; n < 16; ++n) {
#pragma unroll
    for (int j = 0; j < 4; ++j) {
      int row = wv * 16 + lhi * 4 + j;
      int colb = (n * 16 + l15) * 2;
      int byte = row * 512 + (colb ^ ((row & 7) << 4));
      unsigned short hq = f2bf(accQ[n][j] + bias[n]);
      unsigned short hr = f2bf(accR[n][j] + bias[n]);
      *(unsigned short*)(bufQ + byte) = hq;
      *(unsigned short*)(bufR + byte) = hr;
      float fq = bf2f(hq), fr = bf2f(hr);
      nQ[j] += fq * fq;
      nR[j] += fr * fr;
    }
  }
#pragma unroll
  for (int d = 1; d < 16; d <<= 1) {
#pragma unroll
    for (int j = 0; j < 4; ++j) { nQ[j] += __shfl_xor(nQ[j], d); nR[j] += __shfl_xor(nR[j], d); }
  }
  __syncthreads();   // all P tiles staged

  // ========= qr GEMM: qr[k][m] = sum_d Pq[k][d]*Pr[m][d] =========
  f32x4 accC[4];
#pragma unroll
  for (int n = 0; n < 4; ++n) accC[n] = z4;
#pragma unroll
  for (int ks = 0; ks < 8; ++ks) {
    int koffb = ks * 64 + ksub;
    int abyte = abase + (koffb ^ asw);
    s16x8 aQ = *(const s16x8*)(bufQ + abyte);
#pragma unroll
    for (int n = 0; n < 4; ++n) {
      int rrow = n * 16 + l15;
      int bbyte = rrow * 512 + (koffb ^ ((rrow & 7) << 4));
      s16x8 bR = *(const s16x8*)(bufR + bbyte);
      accC[n] = MFMA16(aQ, bR, accC[n]);
    }
  }
  __syncthreads();   // all LDS frag reads done -> bufQ reusable

  float* r2s = (float*)bufQ;   // 64 floats
  if (l15 == 0) {
#pragma unroll
    for (int j = 0; j < 4; ++j) r2s[wv * 16 + lhi * 4 + j] = nR[j];
  }
  __syncthreads();

  // C = sqrt(max(q2 + r2 - 2*qr, 0)) -> direct global store
  float* Cb = out + OFF_C + (size_t)b * 4096;
#pragma unroll
  for (int n = 0; n < 4; ++n) {
#pragma unroll
    for (int j = 0; j < 4; ++j) {
      int k = wv * 16 + lhi * 4 + j;
      int m = n * 16 + l15;
      float d2 = nQ[j] + r2s[m] - 2.0f * accC[n][j];
      Cb[k * 64 + m] = sqrtf(fmaxf(d2, 0.0f));
    }
  }
}

// ======================= Kernel B: Sinkhorn + MESH + outputs =======================
__global__ void __launch_bounds__(256, 4)
sinkhorn_solve(const float* __restrict__ mask_r, float* __restrict__ out) {
  __shared__ float tile[64 * 65];   // C load staging, then T tile for MESH
  __shared__ float u_arr[64], w_arr[64], red[4];

  const int b    = blockIdx.x;
  const int tid  = threadIdx.x;
  const int wv   = tid >> 6;
  const int lane = tid & 63;
  const int rk   = tid >> 2;    // row (or col) this thread group owns
  const int g    = tid & 3;     // 4-lane split of the 64-wide reduction
  const int e0   = g * 16;

  const float* Cb = out + OFF_C + (size_t)b * 4096;

  // load C coalesced -> LDS tile
#pragma unroll
  for (int i = 0; i < 16; ++i) {
    int idx = tid + 256 * i;
    tile[(idx >> 6) * 65 + (idx & 63)] = Cb[idx];
  }
  if (tid < 64) w_arr[tid] = __logf(fmaxf(mask_r[(size_t)b * 64 + tid], 1e-8f));
  __syncthreads();

  // C slices into registers: cn = row slice * (-1/eps), cc = col slice * (-1/eps)
  float cn[16], cc[16];
#pragma unroll
  for (int i = 0; i < 16; ++i) {
    cn[i] = tile[rk * 65 + e0 + i] * -20.0f;
    cc[i] = tile[(e0 + i) * 65 + rk] * -20.0f;
  }

  // ---------------- Sinkhorn: u = -lse_m(cn + w); w = -lse_k(cc + u) ----------------
  for (int it = 0; it < 20; ++it) {
    {
      float v[16];
#pragma unroll
      for (int i = 0; i < 16; ++i) v[i] = cn[i] + w_arr[e0 + i];
      float mx = v[0];
#pragma unroll
      for (int i = 1; i < 16; ++i) mx = fmaxf(mx, v[i]);
      float s = 0.0f;
#pragma unroll
      for (int i = 0; i < 16; ++i) s += __expf(v[i] - mx);
#pragma unroll
      for (int d = 1; d < 4; d <<= 1) {
        float mo = __shfl_xor(mx, d), so = __shfl_xor(s, d);
        float nm = fmaxf(mx, mo);
        s = s * __expf(mx - nm) + so * __expf(mo - nm);
        mx = nm;
      }
      if (g == 0) u_arr[rk] = -(mx + __logf(s));
    }
    __syncthreads();
    {
      float v[16];
#pragma unroll
      for (int i = 0; i < 16; ++i) v[i] = cc[i] + u_arr[e0 + i];
      float mx = v[0];
#pragma unroll
      for (int i = 1; i < 16; ++i) mx = fmaxf(mx, v[i]);
      float s = 0.0f;
#pragma unroll
      for (int i = 0; i < 16; ++i) s += __expf(v[i] - mx);
#pragma unroll
      for (int d = 1; d < 4; d <<= 1) {
        float mo = __shfl_xor(mx, d), so = __shfl_xor(s, d);
        float nm = fmaxf(mx, mo);
        s = s * __expf(mx - nm) + so * __expf(mo - nm);
        mx = nm;
      }
      if (g == 0) w_arr[rk] = -(mx + __logf(s));
    }
    __syncthreads();
  }

  // ---------------- T = exp(cn + u + w), then MESH x3 ----------------
  float t[16];
  {
    float uk = u_arr[rk];
#pragma unroll
    for (int i = 0; i < 16; ++i) t[i] = __expf(cn[i] + uk + w_arr[e0 + i]);
  }
  for (int it = 0; it < 3; ++it) {
    if (it > 0) {
      __syncthreads();
#pragma unroll
      for (int i = 0; i < 16; ++i) t[i] = tile[rk * 65 + e0 + i];
    }
    // row: square + normalize by rowsum
    float s = 0.0f;
#pragma unroll
    for (int i = 0; i < 16; ++i) { t[i] *= t[i]; s += t[i]; }
    s += __shfl_xor(s, 1); s += __shfl_xor(s, 2);
    float inv = 1.0f / (s + 1e-8f);
#pragma unroll
    for (int i = 0; i < 16; ++i) tile[rk * 65 + e0 + i] = t[i] * inv;
    __syncthreads();
    // col: normalize by colsum
    float tc[16]; float cs = 0.0f;
#pragma unroll
    for (int i = 0; i < 16; ++i) { tc[i] = tile[(e0 + i) * 65 + rk]; cs += tc[i]; }
    cs += __shfl_xor(cs, 1); cs += __shfl_xor(cs, 2);
    inv = 1.0f / (cs + 1e-8f);
#pragma unroll
    for (int i = 0; i < 16; ++i) tile[(e0 + i) * 65 + rk] = tc[i] * inv;
  }
  __syncthreads();

  // ---------------- transport cost + similarity + T store ----------------
  {
    float part = 0.0f;
#pragma unroll
    for (int i = 0; i < 16; ++i)
      part += tile[rk * 65 + e0 + i] * (cn[i] * -0.05f);
#pragma unroll
    for (int d = 1; d < 64; d <<= 1) part += __shfl_xor(part, d);
    if (lane == 0) red[wv] = part;
  }
  __syncthreads();
  if (tid == 0) {
    float tc = red[0] + red[1] + red[2] + red[3];
    out[OFF_TC + b] = tc;
    out[b] = 1.0f / (1.0f + __expf(tc));
  }
  {
    float* Tout = out + OFF_T + (size_t)b * 4096;
#pragma unroll
    for (int i = 0; i < 16; ++i) {
      int idx = tid + 256 * i;
      Tout[idx] = tile[(idx >> 6) * 65 + (idx & 63)];
    }
  }
}

extern "C" void kernel_launch(void* const* d_in, const int* in_sizes, int n_in,
                              void* d_out, int out_size, void* d_ws, size_t ws_size,
                              hipStream_t stream) {
  const float* slots_q = (const float*)d_in[0];
  const float* slots_r = (const float*)d_in[1];
  // d_in[2] = mask_q: cancels out of T/T_hard/C/cost (row-rescaling invariance).
  const float* mask_r = (const float*)d_in[3];
  const float* W1 = (const float*)d_in[4];
  const float* b1 = (const float*)d_in[5];
  const float* W2 = (const float*)d_in[6];
  const float* b2 = (const float*)d_in[7];

  short* W1t = (short*)d_ws;            // 256x256 bf16 transposed
  short* W2t = W1t + 65536;

  prep_w_kernel<<<256, 256, 0, stream>>>(W1, W2, W1t, W2t);
  proj_cost_kernel<<<2048, 256, 0, stream>>>(slots_q, slots_r, W1t, W2t, b1, b2,
                                             (float*)d_out);
  sinkhorn_solve<<<2048, 256, 0, stream>>>(mask_r, (float*)d_out);
}

// Round 3
// 292.921 us; speedup vs baseline: 1.6100x; 1.4766x over previous
//
#include <hip/hip_runtime.h>

// SinkhornOT — round 2: N-split waves in proj_cost (each wave owns a 64-col
// output slice -> 4x fewer W-fragment gathers, register-double-buffered).
// B=2048, K=M=64, D=256, eps=0.05, 20 sinkhorn iters, 3 MESH iters.

typedef __attribute__((ext_vector_type(8))) short s16x8;
typedef __attribute__((ext_vector_type(4))) float f32x4;

#define OFF_T  2048
#define OFF_C  (2048 + 2048 * 4096)
#define OFF_TC (2048 + 2 * 2048 * 4096)

__device__ __forceinline__ unsigned short f2bf(float x) {  // RNE f32->bf16
  unsigned u = __builtin_bit_cast(unsigned, x);
  u += 0x7fffu + ((u >> 16) & 1u);
  return (unsigned short)(u >> 16);
}
__device__ __forceinline__ float bf2f(unsigned short h) {
  return __builtin_bit_cast(float, ((unsigned)h) << 16);
}

#define MFMA16(a, b, c) __builtin_amdgcn_mfma_f32_16x16x32_bf16((a), (b), (c), 0, 0, 0)

__global__ void __launch_bounds__(256)
prep_w_kernel(const float* __restrict__ W1, const float* __restrict__ W2,
              short* __restrict__ W1t, short* __restrict__ W2t) {
  int i = blockIdx.x * 256 + threadIdx.x;   // 65536 threads exactly
  int d = i >> 8, e = i & 255;
  W1t[e * 256 + d] = (short)f2bf(W1[i]);
  W2t[e * 256 + d] = (short)f2bf(W2[i]);
}

// K-loop for the two projection GEMMs. Wave computes all 8 row-frags x its
// 4 col-frags. W fragments double-buffered in registers (4 in flight).
__device__ __forceinline__ void gemm_kloop(const short* __restrict__ wb,
                                           const char* sm, int abase0, int asw,
                                           int koff0, f32x4 (&acc)[8][4]) {
  s16x8 bwc[4], bwn[4];
#pragma unroll
  for (int nf = 0; nf < 4; ++nf) bwc[nf] = *(const s16x8*)(wb + nf * 4096);
#pragma unroll
  for (int ks = 0; ks < 8; ++ks) {
    if (ks < 7) {
#pragma unroll
      for (int nf = 0; nf < 4; ++nf)
        bwn[nf] = *(const s16x8*)(wb + nf * 4096 + (ks + 1) * 32);
    }
    const int ko = (ks * 64 + koff0) ^ asw;
    s16x8 af[8];
#pragma unroll
    for (int rf = 0; rf < 8; ++rf)
      af[rf] = *(const s16x8*)(sm + rf * 8192 + abase0 + ko);
#pragma unroll
    for (int rf = 0; rf < 8; ++rf)
#pragma unroll
      for (int nf = 0; nf < 4; ++nf)
        acc[rf][nf] = MFMA16(af[rf], bwc[nf], acc[rf][nf]);
    if (ks < 7) {
#pragma unroll
      for (int nf = 0; nf < 4; ++nf) bwc[nf] = bwn[nf];
    }
  }
}

// ======================= Kernel A: projections + cdist =======================
__global__ void __launch_bounds__(256, 2)
proj_cost_kernel(const float* __restrict__ slots_q, const float* __restrict__ slots_r,
                 const short* __restrict__ W1t, const short* __restrict__ W2t,
                 const float* __restrict__ b1, const float* __restrict__ b2,
                 float* __restrict__ out) {
  // [128 rows][512 B] swizzled bf16 tile: X -> H -> P (rows 0-63 Q, 64-127 R).
  // After qr-GEMM frees it, head reused as norm-partials buffer [4][128] f32.
  __shared__ char smem[65536];
  float* nbuf = (float*)smem;

  const int b    = blockIdx.x;
  const int tid  = threadIdx.x;
  const int wv   = tid >> 6;
  const int lane = tid & 63;
  const int l15  = lane & 15;
  const int lhi  = lane >> 4;

  // ---------- stage X (f32 -> bf16, swizzled) ----------
  {
    const float* sq = slots_q + (size_t)b * 16384;
    const float* sr = slots_r + (size_t)b * 16384;
#pragma unroll
    for (int i = 0; i < 32; ++i) {
      int idx4 = tid + 256 * i;               // float4 index, rows = idx4>>6
      int row = idx4 >> 6;                    // 0..127 (i<16 -> Q, else R)
      int colb = (idx4 & 63) * 8;
      const float* src = (i < 16) ? (sq + idx4 * 4) : (sr + idx4 * 4 - 16384);
      float4 v = *(const float4*)src;
      unsigned lo = (unsigned)f2bf(v.x) | ((unsigned)f2bf(v.y) << 16);
      unsigned hi = (unsigned)f2bf(v.z) | ((unsigned)f2bf(v.w) << 16);
      *(uint2*)(smem + row * 512 + (colb ^ ((row & 7) << 4))) = make_uint2(lo, hi);
    }
  }
  __syncthreads();

  const int abase0 = l15 * 512;          // A-frag lane row base (row = rf*16+l15)
  const int asw    = (l15 & 7) << 4;     // swizzle (row&7 == l15&7 for all frags)
  const int koff0  = lhi * 16;           // byte sub-offset within 64B k-step
  const short* wb1 = W1t + (wv * 64 + l15) * 256 + lhi * 8;
  const short* wb2 = W2t + (wv * 64 + l15) * 256 + lhi * 8;

  float b1v[4], b2v[4];
#pragma unroll
  for (int nf = 0; nf < 4; ++nf) {
    b1v[nf] = b1[wv * 64 + nf * 16 + l15];
    b2v[nf] = b2[wv * 64 + nf * 16 + l15];
  }

  const f32x4 z4 = {0.f, 0.f, 0.f, 0.f};
  f32x4 acc[8][4];

  // ================= GEMM1: H = relu(X*W1 + b1) =================
#pragma unroll
  for (int rf = 0; rf < 8; ++rf)
#pragma unroll
    for (int nf = 0; nf < 4; ++nf) acc[rf][nf] = z4;
  gemm_kloop(wb1, smem, abase0, asw, koff0, acc);
  __syncthreads();   // all waves done reading X
#pragma unroll
  for (int rf = 0; rf < 8; ++rf)
#pragma unroll
    for (int nf = 0; nf < 4; ++nf)
#pragma unroll
      for (int j = 0; j < 4; ++j) {
        int row = rf * 16 + lhi * 4 + j;
        int colb = (wv * 64 + nf * 16 + l15) * 2;
        *(unsigned short*)(smem + row * 512 + (colb ^ ((row & 7) << 4))) =
            f2bf(fmaxf(acc[rf][nf][j] + b1v[nf], 0.0f));
      }
  __syncthreads();

  // ================= GEMM2: P = H*W2 + b2 (+ norm partials) =================
#pragma unroll
  for (int rf = 0; rf < 8; ++rf)
#pragma unroll
    for (int nf = 0; nf < 4; ++nf) acc[rf][nf] = z4;
  gemm_kloop(wb2, smem, abase0, asw, koff0, acc);
  __syncthreads();   // all waves done reading H

  float p2[8][4];
#pragma unroll
  for (int rf = 0; rf < 8; ++rf)
#pragma unroll
    for (int j = 0; j < 4; ++j) {
      float s = 0.0f;
#pragma unroll
      for (int nf = 0; nf < 4; ++nf) {
        unsigned short h = f2bf(acc[rf][nf][j] + b2v[nf]);
        int row = rf * 16 + lhi * 4 + j;
        int colb = (wv * 64 + nf * 16 + l15) * 2;
        *(unsigned short*)(smem + row * 512 + (colb ^ ((row & 7) << 4))) = h;
        float f = bf2f(h);
        s += f * f;
      }
      p2[rf][j] = s;
    }
  // reduce partials over the 16-lane col-group -> per-wave row partials
#pragma unroll
  for (int d = 1; d < 16; d <<= 1)
#pragma unroll
    for (int rf = 0; rf < 8; ++rf)
#pragma unroll
      for (int j = 0; j < 4; ++j) p2[rf][j] += __shfl_xor(p2[rf][j], d);
  __syncthreads();   // P staged

  // ========= qr GEMM (M-split): qr[k][m] = sum_d Pq[k][d]*Pr[m][d] =========
  f32x4 accC[4];
#pragma unroll
  for (int n = 0; n < 4; ++n) accC[n] = z4;
#pragma unroll
  for (int ks = 0; ks < 8; ++ks) {
    const int ko = (ks * 64 + koff0) ^ asw;   // rows here also have row&7==l15&7
    s16x8 aQ = *(const s16x8*)(smem + wv * 8192 + abase0 + ko);
#pragma unroll
    for (int n = 0; n < 4; ++n) {
      s16x8 bR = *(const s16x8*)(smem + 32768 + n * 8192 + abase0 + ko);
      accC[n] = MFMA16(aQ, bR, accC[n]);
    }
  }
  __syncthreads();   // P reads done -> tile region free for norm exchange

  if (l15 == 0) {
#pragma unroll
    for (int rf = 0; rf < 8; ++rf) {
      f32x4 v = {p2[rf][0], p2[rf][1], p2[rf][2], p2[rf][3]};
      *(f32x4*)(nbuf + wv * 128 + rf * 16 + lhi * 4) = v;
    }
  }
  __syncthreads();

  f32x4 nq = z4;
#pragma unroll
  for (int w = 0; w < 4; ++w)
    nq += *(const f32x4*)(nbuf + w * 128 + wv * 16 + lhi * 4);
  float nR[4];
#pragma unroll
  for (int n = 0; n < 4; ++n) {
    float s = 0.0f;
#pragma unroll
    for (int w = 0; w < 4; ++w) s += nbuf[w * 128 + 64 + n * 16 + l15];
    nR[n] = s;
  }

  // C = sqrt(max(q2 + r2 - 2*qr, 0)) -> direct global store
  float* Cb = out + OFF_C + (size_t)b * 4096;
#pragma unroll
  for (int n = 0; n < 4; ++n)
#pragma unroll
    for (int j = 0; j < 4; ++j) {
      float d2 = nq[j] + nR[n] - 2.0f * accC[n][j];
      Cb[(wv * 16 + lhi * 4 + j) * 64 + n * 16 + l15] = sqrtf(fmaxf(d2, 0.0f));
    }
}

// ======================= Kernel B: Sinkhorn + MESH + outputs =======================
__global__ void __launch_bounds__(256, 4)
sinkhorn_solve(const float* __restrict__ mask_r, float* __restrict__ out) {
  __shared__ float tile[64 * 65];   // C load staging, then T tile for MESH
  __shared__ float u_arr[64], w_arr[64], red[4];

  const int b    = blockIdx.x;
  const int tid  = threadIdx.x;
  const int wv   = tid >> 6;
  const int lane = tid & 63;
  const int rk   = tid >> 2;    // row (or col) this thread group owns
  const int g    = tid & 3;     // 4-lane split of the 64-wide reduction
  const int e0   = g * 16;

  const float* Cb = out + OFF_C + (size_t)b * 4096;

  // load C coalesced -> LDS tile
#pragma unroll
  for (int i = 0; i < 16; ++i) {
    int idx = tid + 256 * i;
    tile[(idx >> 6) * 65 + (idx & 63)] = Cb[idx];
  }
  if (tid < 64) w_arr[tid] = __logf(fmaxf(mask_r[(size_t)b * 64 + tid], 1e-8f));
  __syncthreads();

  // C slices into registers: cn = row slice * (-1/eps), cc = col slice * (-1/eps)
  float cn[16], cc[16];
#pragma unroll
  for (int i = 0; i < 16; ++i) {
    cn[i] = tile[rk * 65 + e0 + i] * -20.0f;
    cc[i] = tile[(e0 + i) * 65 + rk] * -20.0f;
  }

  // ---------------- Sinkhorn: u = -lse_m(cn + w); w = -lse_k(cc + u) ----------------
  for (int it = 0; it < 20; ++it) {
    {
      float v[16];
#pragma unroll
      for (int i = 0; i < 16; ++i) v[i] = cn[i] + w_arr[e0 + i];
      float mx = v[0];
#pragma unroll
      for (int i = 1; i < 16; ++i) mx = fmaxf(mx, v[i]);
      float s = 0.0f;
#pragma unroll
      for (int i = 0; i < 16; ++i) s += __expf(v[i] - mx);
#pragma unroll
      for (int d = 1; d < 4; d <<= 1) {
        float mo = __shfl_xor(mx, d), so = __shfl_xor(s, d);
        float nm = fmaxf(mx, mo);
        s = s * __expf(mx - nm) + so * __expf(mo - nm);
        mx = nm;
      }
      if (g == 0) u_arr[rk] = -(mx + __logf(s));
    }
    __syncthreads();
    {
      float v[16];
#pragma unroll
      for (int i = 0; i < 16; ++i) v[i] = cc[i] + u_arr[e0 + i];
      float mx = v[0];
#pragma unroll
      for (int i = 1; i < 16; ++i) mx = fmaxf(mx, v[i]);
      float s = 0.0f;
#pragma unroll
      for (int i = 0; i < 16; ++i) s += __expf(v[i] - mx);
#pragma unroll
      for (int d = 1; d < 4; d <<= 1) {
        float mo = __shfl_xor(mx, d), so = __shfl_xor(s, d);
        float nm = fmaxf(mx, mo);
        s = s * __expf(mx - nm) + so * __expf(mo - nm);
        mx = nm;
      }
      if (g == 0) w_arr[rk] = -(mx + __logf(s));
    }
    __syncthreads();
  }

  // ---------------- T = exp(cn + u + w), then MESH x3 ----------------
  float t[16];
  {
    float uk = u_arr[rk];
#pragma unroll
    for (int i = 0; i < 16; ++i) t[i] = __expf(cn[i] + uk + w_arr[e0 + i]);
  }
  for (int it = 0; it < 3; ++it) {
    if (it > 0) {
      __syncthreads();
#pragma unroll
      for (int i = 0; i < 16; ++i) t[i] = tile[rk * 65 + e0 + i];
    }
    // row: square + normalize by rowsum
    float s = 0.0f;
#pragma unroll
    for (int i = 0; i < 16; ++i) { t[i] *= t[i]; s += t[i]; }
    s += __shfl_xor(s, 1); s += __shfl_xor(s, 2);
    float inv = 1.0f / (s + 1e-8f);
#pragma unroll
    for (int i = 0; i < 16; ++i) tile[rk * 65 + e0 + i] = t[i] * inv;
    __syncthreads();
    // col: normalize by colsum
    float tc[16]; float cs = 0.0f;
#pragma unroll
    for (int i = 0; i < 16; ++i) { tc[i] = tile[(e0 + i) * 65 + rk]; cs += tc[i]; }
    cs += __shfl_xor(cs, 1); cs += __shfl_xor(cs, 2);
    inv = 1.0f / (cs + 1e-8f);
#pragma unroll
    for (int i = 0; i < 16; ++i) tile[(e0 + i) * 65 + rk] = tc[i] * inv;
  }
  __syncthreads();

  // ---------------- transport cost + similarity + T store ----------------
  {
    float part = 0.0f;
#pragma unroll
    for (int i = 0; i < 16; ++i)
      part += tile[rk * 65 + e0 + i] * (cn[i] * -0.05f);
#pragma unroll
    for (int d = 1; d < 64; d <<= 1) part += __shfl_xor(part, d);
    if (lane == 0) red[wv] = part;
  }
  __syncthreads();
  if (tid == 0) {
    float tc = red[0] + red[1] + red[2] + red[3];
    out[OFF_TC + b] = tc;
    out[b] = 1.0f / (1.0f + __expf(tc));
  }
  {
    float* Tout = out + OFF_T + (size_t)b * 4096;
#pragma unroll
    for (int i = 0; i < 16; ++i) {
      int idx = tid + 256 * i;
      Tout[idx] = tile[(idx >> 6) * 65 + (idx & 63)];
    }
  }
}

extern "C" void kernel_launch(void* const* d_in, const int* in_sizes, int n_in,
                              void* d_out, int out_size, void* d_ws, size_t ws_size,
                              hipStream_t stream) {
  const float* slots_q = (const float*)d_in[0];
  const float* slots_r = (const float*)d_in[1];
  // d_in[2] = mask_q: cancels out of T/T_hard/C/cost (row-rescaling invariance).
  const float* mask_r = (const float*)d_in[3];
  const float* W1 = (const float*)d_in[4];
  const float* b1 = (const float*)d_in[5];
  const float* W2 = (const float*)d_in[6];
  const float* b2 = (const float*)d_in[7];

  short* W1t = (short*)d_ws;            // 256x256 bf16 transposed
  short* W2t = W1t + 65536;

  prep_w_kernel<<<256, 256, 0, stream>>>(W1, W2, W1t, W2t);
  proj_cost_kernel<<<2048, 256, 0, stream>>>(slots_q, slots_r, W1t, W2t, b1, b2,
                                             (float*)d_out);
  sinkhorn_solve<<<2048, 256, 0, stream>>>(mask_r, (float*)d_out);
}